// Round 3
// baseline (62.738 us; speedup 1.0000x reference)
//
#include <hip/hip_runtime.h>

// Problem constants (from reference)
#define B 1024
#define R 256
#define D 512
#define G 4

#define LOG2E 1.44269504088896340736f

// Workspace layout (float offsets). Total = 822272 floats = 3.29 MB.
#define OFF_FA   0                       // [R][D]   fa = -kappa*tanh(isp)*log2e
#define OFF_FB   (R*D)                   // [R][D]   fb = -fa*th
#define OFF_SAG  (2*R*D)                 // [R][G][D] sag_g = m*e_sign*A_g
#define OFF_EPI  (2*R*D + G*R*D)         // [R][12]  {offe0..3, gm0..3, k8e, hw, pad, pad}
#define OFF_PART (OFF_EPI + R*12)        // [32][B]  per-r-group partial of y
#define NRG 32                           // r-groups (8 r per block)
#define NBG 16                           // b-groups (64 b per block)

__device__ __forceinline__ float sig_precise(float v) {
    return 1.0f / (1.0f + expf(-v));
}

// ---------------- Kernel 1: fold all b-independent math ----------------
__global__ __launch_bounds__(256)
void sge_precompute(const float* __restrict__ th,  const float* __restrict__ isp,
                    const float* __restrict__ esp, const float* __restrict__ ml,
                    const float* __restrict__ lk,  const float* __restrict__ gl,
                    const float* __restrict__ tg,  const float* __restrict__ gml,
                    const float* __restrict__ kf,  const float* __restrict__ hw,
                    float* __restrict__ ws)
{
    const int r   = blockIdx.x;
    const int tid = threadIdx.x;
    __shared__ float4 red[256];

    float kappa = expf(lk[0]);
    kappa = fminf(fmaxf(kappa, 0.5f), 50.0f);

    float4 psum = make_float4(0.f, 0.f, 0.f, 0.f);
    for (int d = tid; d < D; d += 256) {
        const int idx = r * D + d;
        const float thv  = th[idx];
        const float ineq = tanhf(isp[idx]);
        const float es   = tanhf(esp[idx]);
        const float mm   = sig_precise(ml[idx]);
        // softmax over g (axis 0) of group_logits[:, d]
        const float g0 = gl[0*D + d], g1 = gl[1*D + d], g2 = gl[2*D + d], g3 = gl[3*D + d];
        const float mx = fmaxf(fmaxf(g0, g1), fmaxf(g2, g3));
        const float e0 = expf(g0 - mx), e1 = expf(g1 - mx), e2 = expf(g2 - mx), e3 = expf(g3 - mx);
        const float inv = 1.0f / (e0 + e1 + e2 + e3);
        const float a0 = e0 * inv, a1 = e1 * inv, a2 = e2 * inv, a3 = e3 * inv;

        const float fa = -kappa * ineq * LOG2E;   // exp2(fa*x + fb) == exp(-kappa*ineq*(x-th))
        const float fb = -fa * thv;
        const float s  = mm * es;
        const float s0 = s * a0, s1 = s * a1, s2 = s * a2, s3 = s * a3;

        ws[OFF_FA + idx] = fa;
        ws[OFF_FB + idx] = fb;
        ws[OFF_SAG + (r * G + 0) * D + d] = s0;
        ws[OFF_SAG + (r * G + 1) * D + d] = s1;
        ws[OFF_SAG + (r * G + 2) * D + d] = s2;
        ws[OFF_SAG + (r * G + 3) * D + d] = s3;
        psum.x += s0; psum.y += s1; psum.z += s2; psum.w += s3;
    }
    red[tid] = psum;
    __syncthreads();
    for (int s = 128; s > 0; s >>= 1) {
        if (tid < s) {
            red[tid].x += red[tid + s].x;
            red[tid].y += red[tid + s].y;
            red[tid].z += red[tid + s].z;
            red[tid].w += red[tid + s].w;
        }
        __syncthreads();
    }
    if (tid == 0) {
        const float4 base = red[0];
        const float gm0 = sig_precise(gml[r * G + 0]);
        const float gm1 = sig_precise(gml[r * G + 1]);
        const float gm2 = sig_precise(gml[r * G + 2]);
        const float gm3 = sig_precise(gml[r * G + 3]);
        const float en  = gm0 + gm1 + gm2 + gm3 + 1e-6f;
        const float k   = sig_precise(kf[r]) * en;
        float* epi = ws + OFF_EPI + r * 12;
        // pg_g = sigmoid(12*acc_g - 6*(base_g+tg_g))  ->  exp2 arg = fma(C12, acc, offe)
        epi[0] = 6.0f * (base.x + tg[r * G + 0]) * LOG2E;
        epi[1] = 6.0f * (base.y + tg[r * G + 1]) * LOG2E;
        epi[2] = 6.0f * (base.z + tg[r * G + 2]) * LOG2E;
        epi[3] = 6.0f * (base.w + tg[r * G + 3]) * LOG2E;
        epi[4] = gm0; epi[5] = gm1; epi[6] = gm2; epi[7] = gm3;
        epi[8] = 8.0f * k * LOG2E;   // z = sigmoid(8*score - 8k) -> exp2 arg = fma(C8, score, k8e)
        epi[9] = hw[r];
        epi[10] = 0.f; epi[11] = 0.f;
    }
}

// ---------------- Kernel 2: the 134M-element hot loop ----------------
// Block: 512 threads = 8 waves. Wave w handles r = rg*8+w for 64 b's (one per lane).
// x tile staged in LDS in two 256-d halves (65 KB -> 2 blocks/CU, 4 waves/SIMD).
// Per-(r,d) params read at wave-uniform addresses -> s_load -> SGPR operands.
__global__ __launch_bounds__(512, 4)
void sge_main(const float* __restrict__ x, const float* __restrict__ ws,
              float* __restrict__ part)
{
    __shared__ float xl[64 * 260];   // pitch 260 floats: 16B aligned rows, conflict-free b128 reads
    __shared__ float zbuf[512];

    const int tid  = threadIdx.x;
    const int lane = tid & 63;
    const int w    = __builtin_amdgcn_readfirstlane(tid >> 6);  // force wave-uniform
    const int bg   = blockIdx.x;   // 0..15
    const int rg   = blockIdx.y;   // 0..31
    const int r    = rg * 8 + w;

    const float* fa_p = ws + OFF_FA + r * D;
    const float* fb_p = ws + OFF_FB + r * D;
    const float* s0_p = ws + OFF_SAG + (r * G + 0) * D;
    const float* s1_p = s0_p + D;
    const float* s2_p = s1_p + D;
    const float* s3_p = s2_p + D;

    float acc0 = 0.f, acc1 = 0.f, acc2 = 0.f, acc3 = 0.f;

    for (int h = 0; h < 2; ++h) {
        __syncthreads();   // all waves done with previous half before overwrite
        // stage 64 rows x 256 cols (as float4), fully coalesced
        for (int i = tid; i < 64 * 64; i += 512) {
            const int row = i >> 6, c4 = i & 63;
            const float4 v = reinterpret_cast<const float4*>(x)[(bg * 64 + row) * (D / 4) + h * 64 + c4];
            *reinterpret_cast<float4*>(&xl[row * 260 + c4 * 4]) = v;
        }
        __syncthreads();

        const int dbase = h * 256;
        for (int d0 = 0; d0 < 256; d0 += 8) {
            // wave-uniform parameter chunk (expect s_load_dwordx8 each)
            float fa[8], fb[8], q0[8], q1[8], q2[8], q3[8];
            #pragma unroll
            for (int k = 0; k < 8; ++k) {
                fa[k] = fa_p[dbase + d0 + k];
                fb[k] = fb_p[dbase + d0 + k];
                q0[k] = s0_p[dbase + d0 + k];
                q1[k] = s1_p[dbase + d0 + k];
                q2[k] = s2_p[dbase + d0 + k];
                q3[k] = s3_p[dbase + d0 + k];
            }
            const float4 xa = *reinterpret_cast<const float4*>(&xl[lane * 260 + d0]);
            const float4 xb = *reinterpret_cast<const float4*>(&xl[lane * 260 + d0 + 4]);
            const float xs[8] = {xa.x, xa.y, xa.z, xa.w, xb.x, xb.y, xb.z, xb.w};
            #pragma unroll
            for (int k = 0; k < 8; ++k) {
                const float t = fmaf(fa[k], xs[k], fb[k]);       // -kappa*ineq*(x-th)*log2e
                const float q = __builtin_amdgcn_exp2f(t);       // v_exp_f32
                const float c = __builtin_amdgcn_rcpf(1.0f + q); // sigmoid, v_rcp_f32
                acc0 = fmaf(q0[k], c, acc0);
                acc1 = fmaf(q1[k], c, acc1);
                acc2 = fmaf(q2[k], c, acc2);
                acc3 = fmaf(q3[k], c, acc3);
            }
        }
    }

    // epilogue: per (b,r) scalar chain, vectorized across lanes (=b)
    const float* epi = ws + OFF_EPI + r * 12;
    const float C12 = -12.0f * LOG2E;
    const float C8  = -8.0f  * LOG2E;
    const float pg0 = __builtin_amdgcn_rcpf(1.0f + __builtin_amdgcn_exp2f(fmaf(C12, acc0, epi[0])));
    const float pg1 = __builtin_amdgcn_rcpf(1.0f + __builtin_amdgcn_exp2f(fmaf(C12, acc1, epi[1])));
    const float pg2 = __builtin_amdgcn_rcpf(1.0f + __builtin_amdgcn_exp2f(fmaf(C12, acc2, epi[2])));
    const float pg3 = __builtin_amdgcn_rcpf(1.0f + __builtin_amdgcn_exp2f(fmaf(C12, acc3, epi[3])));
    float score = pg0 * epi[4];
    score = fmaf(pg1, epi[5], score);
    score = fmaf(pg2, epi[6], score);
    score = fmaf(pg3, epi[7], score);
    const float z = __builtin_amdgcn_rcpf(1.0f + __builtin_amdgcn_exp2f(fmaf(C8, score, epi[8])));
    zbuf[tid] = epi[9] * z;   // hw[r] * z
    __syncthreads();
    if (tid < 64) {
        float s = zbuf[tid];
        #pragma unroll
        for (int ww = 1; ww < 8; ++ww) s += zbuf[ww * 64 + tid];
        part[rg * B + bg * 64 + tid] = s;   // deterministic partial per r-group
    }
}

// ---------------- Kernel 3: deterministic final reduction ----------------
__global__ __launch_bounds__(256)
void sge_finalize(const float* __restrict__ part, const float* __restrict__ hb,
                  float* __restrict__ y)
{
    const int b = blockIdx.x * 256 + threadIdx.x;
    float s = hb[0];
    #pragma unroll
    for (int rg = 0; rg < NRG; ++rg) s += part[rg * B + b];
    y[b] = s;
}

extern "C" void kernel_launch(void* const* d_in, const int* in_sizes, int n_in,
                              void* d_out, int out_size, void* d_ws, size_t ws_size,
                              hipStream_t stream)
{
    const float* x   = (const float*)d_in[0];
    const float* th  = (const float*)d_in[1];
    const float* isp = (const float*)d_in[2];
    const float* esp = (const float*)d_in[3];
    const float* ml  = (const float*)d_in[4];
    const float* lk  = (const float*)d_in[5];
    const float* gl  = (const float*)d_in[6];
    const float* tg  = (const float*)d_in[7];
    const float* gml = (const float*)d_in[8];
    const float* kf  = (const float*)d_in[9];
    const float* hw  = (const float*)d_in[10];
    const float* hb  = (const float*)d_in[11];
    float* ws = (float*)d_ws;
    float* y  = (float*)d_out;

    sge_precompute<<<R, 256, 0, stream>>>(th, isp, esp, ml, lk, gl, tg, gml, kf, hw, ws);
    sge_main<<<dim3(NBG, NRG), 512, 0, stream>>>(x, ws, ws + OFF_PART);
    sge_finalize<<<B / 256, 256, 0, stream>>>(ws + OFF_PART, hb, y);
}

// Round 4
// 55.830 us; speedup vs baseline: 1.1237x; 1.1237x over previous
//
#include <hip/hip_runtime.h>

// Problem constants (from reference)
#define B 1024
#define R 256
#define D 512
#define G 4

#define LOG2E 1.44269504088896340736f

// Workspace layout (float offsets). Total = 822272 floats = 3.29 MB.
// PB: per (r, chunk-of-8-d) interleaved params: [th(8) | fa(8) | q0(8) | q1(8) | q2(8) | q3(8)]
//   fa = -kappa*tanh(isp)*LOG2E ;  t' = (x - th)*fa ;  sigmoid = 1/(1+exp2(t'))
//   qg = sigmoid(ml)*tanh(esp)*softmax(A)_g
#define OFF_PB   0                       // [R][64][48]
#define OFF_EPI  (R*64*48)               // [R][12]  {offe0..3, gm0..3, k8e, hw, pad, pad}
#define OFF_PART (OFF_EPI + R*12)        // [32][B]  per-r-group partial of y
#define NRG 32                           // r-groups (8 r per block)
#define NBG 16                           // b-groups (64 b per block)

typedef float f2 __attribute__((ext_vector_type(2)));

static __device__ __forceinline__ f2 mk2(float a, float b) { f2 v; v.x = a; v.y = b; return v; }

__device__ __forceinline__ float sig_precise(float v) {
    return 1.0f / (1.0f + expf(-v));
}

// ---------------- Kernel 1: fold all b-independent math ----------------
__global__ __launch_bounds__(256)
void sge_precompute(const float* __restrict__ th,  const float* __restrict__ isp,
                    const float* __restrict__ esp, const float* __restrict__ ml,
                    const float* __restrict__ lk,  const float* __restrict__ gl,
                    const float* __restrict__ tg,  const float* __restrict__ gml,
                    const float* __restrict__ kf,  const float* __restrict__ hw,
                    float* __restrict__ ws)
{
    const int r   = blockIdx.x;
    const int tid = threadIdx.x;
    __shared__ float4 red[256];

    float kappa = expf(lk[0]);
    kappa = fminf(fmaxf(kappa, 0.5f), 50.0f);

    float4 psum = make_float4(0.f, 0.f, 0.f, 0.f);
    for (int d = tid; d < D; d += 256) {
        const int idx = r * D + d;
        const float thv  = th[idx];
        const float ineq = tanhf(isp[idx]);
        const float es   = tanhf(esp[idx]);
        const float mm   = sig_precise(ml[idx]);
        // softmax over g (axis 0) of group_logits[:, d]
        const float g0 = gl[0*D + d], g1 = gl[1*D + d], g2 = gl[2*D + d], g3 = gl[3*D + d];
        const float mx = fmaxf(fmaxf(g0, g1), fmaxf(g2, g3));
        const float e0 = expf(g0 - mx), e1 = expf(g1 - mx), e2 = expf(g2 - mx), e3 = expf(g3 - mx);
        const float inv = 1.0f / (e0 + e1 + e2 + e3);
        const float a0 = e0 * inv, a1 = e1 * inv, a2 = e2 * inv, a3 = e3 * inv;

        const float fa = -kappa * ineq * LOG2E;   // exp2((x-th)*fa) == exp(-kappa*ineq*(x-th))
        const float s  = mm * es;
        const float s0 = s * a0, s1 = s * a1, s2 = s * a2, s3 = s * a3;

        const int chunk = d >> 3, j = d & 7;
        float* pc = ws + OFF_PB + (size_t)(r * 64 + chunk) * 48;
        pc[j]      = thv;
        pc[8 + j]  = fa;
        pc[16 + j] = s0;
        pc[24 + j] = s1;
        pc[32 + j] = s2;
        pc[40 + j] = s3;
        psum.x += s0; psum.y += s1; psum.z += s2; psum.w += s3;
    }
    red[tid] = psum;
    __syncthreads();
    for (int s = 128; s > 0; s >>= 1) {
        if (tid < s) {
            red[tid].x += red[tid + s].x;
            red[tid].y += red[tid + s].y;
            red[tid].z += red[tid + s].z;
            red[tid].w += red[tid + s].w;
        }
        __syncthreads();
    }
    if (tid == 0) {
        const float4 base = red[0];
        const float gm0 = sig_precise(gml[r * G + 0]);
        const float gm1 = sig_precise(gml[r * G + 1]);
        const float gm2 = sig_precise(gml[r * G + 2]);
        const float gm3 = sig_precise(gml[r * G + 3]);
        const float en  = gm0 + gm1 + gm2 + gm3 + 1e-6f;
        const float k   = sig_precise(kf[r]) * en;
        float* epi = ws + OFF_EPI + r * 12;
        // pg_g = sigmoid(12*acc_g - 6*(base_g+tg_g))  ->  exp2 arg = fma(C12, acc, offe)
        epi[0] = 6.0f * (base.x + tg[r * G + 0]) * LOG2E;
        epi[1] = 6.0f * (base.y + tg[r * G + 1]) * LOG2E;
        epi[2] = 6.0f * (base.z + tg[r * G + 2]) * LOG2E;
        epi[3] = 6.0f * (base.w + tg[r * G + 3]) * LOG2E;
        epi[4] = gm0; epi[5] = gm1; epi[6] = gm2; epi[7] = gm3;
        epi[8] = 8.0f * k * LOG2E;   // z = sigmoid(8*score - 8k) -> exp2 arg = fma(C8, score, k8e)
        epi[9] = hw[r];
        epi[10] = 0.f; epi[11] = 0.f;
    }
}

// ---------------- Kernel 2: the 134M-element hot loop ----------------
// Block: 512 threads = 8 waves. Wave w handles r = rg*8+w for 64 b's (one per lane).
// x tile staged in LDS in two 256-d halves. Per-(r,d) params read at wave-uniform
// addresses (expect s_load). Packed fp32 (v_pk_*) for all FMAs; pairwise rcp turns
// 2 sigmoids into {2 exp2, 1 rcp, 3 mul}. Params + x double-buffered at distance 1
// so the per-chunk lgkmcnt drain overlaps the previous chunk's compute.
__global__ __launch_bounds__(512, 4)
void sge_main(const float* __restrict__ x, const float* __restrict__ ws,
              float* __restrict__ part)
{
    __shared__ float xl[64 * 260];   // pitch 260 floats: 16B-aligned rows, conflict-free b128 reads
    __shared__ float zbuf[512];

    const int tid  = threadIdx.x;
    const int lane = tid & 63;
    const int w    = __builtin_amdgcn_readfirstlane(tid >> 6);  // force wave-uniform
    const int bg   = blockIdx.x;   // 0..15
    const int rg   = blockIdx.y;   // 0..31
    const int r    = rg * 8 + w;

    const float* pb = ws + OFF_PB + (size_t)r * (64 * 48);

    f2 acc0 = mk2(0.f, 0.f), acc1 = mk2(0.f, 0.f), acc2 = mk2(0.f, 0.f), acc3 = mk2(0.f, 0.f);

    float pA[48], pB[48];
    float4 xaA, xbA, xaB, xbB;

    auto compute = [&](const float (&p)[48], const float4& xa, const float4& xb) {
        const float xs[8] = {xa.x, xa.y, xa.z, xa.w, xb.x, xb.y, xb.z, xb.w};
        #pragma unroll
        for (int i = 0; i < 4; ++i) {
            const f2 xp  = mk2(xs[2*i],        xs[2*i + 1]);
            const f2 th2 = mk2(p[2*i],         p[2*i + 1]);
            const f2 fa2 = mk2(p[8  + 2*i],    p[9  + 2*i]);
            const f2 t   = (xp - th2) * fa2;            // v_pk_sub / v_pk_mul
            f2 q;
            q.x = __builtin_amdgcn_exp2f(t.x);
            q.y = __builtin_amdgcn_exp2f(t.y);
            const f2 a = q + 1.0f;                      // v_pk_add
            const float rp = __builtin_amdgcn_rcpf(a.x * a.y);   // one rcp for the pair
            const f2 c = mk2(a.y * rp, a.x * rp);       // sigmoid pair
            acc0 = __builtin_elementwise_fma(mk2(p[16 + 2*i], p[17 + 2*i]), c, acc0);
            acc1 = __builtin_elementwise_fma(mk2(p[24 + 2*i], p[25 + 2*i]), c, acc1);
            acc2 = __builtin_elementwise_fma(mk2(p[32 + 2*i], p[33 + 2*i]), c, acc2);
            acc3 = __builtin_elementwise_fma(mk2(p[40 + 2*i], p[41 + 2*i]), c, acc3);
        }
    };

    for (int h = 0; h < 2; ++h) {
        __syncthreads();   // all waves done with previous half before overwrite
        // stage 64 rows x 256 cols (as float4), fully coalesced
        for (int i = tid; i < 64 * 64; i += 512) {
            const int row = i >> 6, c4 = i & 63;
            const float4 v = reinterpret_cast<const float4*>(x)[(bg * 64 + row) * (D / 4) + h * 64 + c4];
            *reinterpret_cast<float4*>(&xl[row * 260 + c4 * 4]) = v;
        }
        __syncthreads();

        // prologue: load chunk 0 of this half
        {
            const float* pc = pb + (h * 32) * 48;
            #pragma unroll
            for (int j = 0; j < 48; ++j) pA[j] = pc[j];
            xaA = *reinterpret_cast<const float4*>(&xl[lane * 260 + 0]);
            xbA = *reinterpret_cast<const float4*>(&xl[lane * 260 + 4]);
        }
        #pragma unroll 1
        for (int c = 0; c < 32; c += 2) {
            // prefetch chunk c+1 while computing chunk c
            {
                const float* pc = pb + (h * 32 + c + 1) * 48;
                #pragma unroll
                for (int j = 0; j < 48; ++j) pB[j] = pc[j];
                xaB = *reinterpret_cast<const float4*>(&xl[lane * 260 + (c + 1) * 8]);
                xbB = *reinterpret_cast<const float4*>(&xl[lane * 260 + (c + 1) * 8 + 4]);
            }
            compute(pA, xaA, xbA);
            // prefetch chunk c+2 (clamped; tail prefetch is dead but harmless)
            {
                const int cn = (c + 2 < 32) ? (c + 2) : 0;
                const float* pc = pb + (h * 32 + cn) * 48;
                #pragma unroll
                for (int j = 0; j < 48; ++j) pA[j] = pc[j];
                xaA = *reinterpret_cast<const float4*>(&xl[lane * 260 + cn * 8]);
                xbA = *reinterpret_cast<const float4*>(&xl[lane * 260 + cn * 8 + 4]);
            }
            compute(pB, xaB, xbB);
        }
    }

    const float a0 = acc0.x + acc0.y;
    const float a1 = acc1.x + acc1.y;
    const float a2 = acc2.x + acc2.y;
    const float a3 = acc3.x + acc3.y;

    // epilogue: per (b,r) scalar chain, vectorized across lanes (=b)
    const float* epi = ws + OFF_EPI + r * 12;
    const float C12 = -12.0f * LOG2E;
    const float C8  = -8.0f  * LOG2E;
    const float pg0 = __builtin_amdgcn_rcpf(1.0f + __builtin_amdgcn_exp2f(fmaf(C12, a0, epi[0])));
    const float pg1 = __builtin_amdgcn_rcpf(1.0f + __builtin_amdgcn_exp2f(fmaf(C12, a1, epi[1])));
    const float pg2 = __builtin_amdgcn_rcpf(1.0f + __builtin_amdgcn_exp2f(fmaf(C12, a2, epi[2])));
    const float pg3 = __builtin_amdgcn_rcpf(1.0f + __builtin_amdgcn_exp2f(fmaf(C12, a3, epi[3])));
    float score = pg0 * epi[4];
    score = fmaf(pg1, epi[5], score);
    score = fmaf(pg2, epi[6], score);
    score = fmaf(pg3, epi[7], score);
    const float z = __builtin_amdgcn_rcpf(1.0f + __builtin_amdgcn_exp2f(fmaf(C8, score, epi[8])));
    zbuf[tid] = epi[9] * z;   // hw[r] * z
    __syncthreads();
    if (tid < 64) {
        float s = zbuf[tid];
        #pragma unroll
        for (int ww = 1; ww < 8; ++ww) s += zbuf[ww * 64 + tid];
        part[rg * B + bg * 64 + tid] = s;   // deterministic partial per r-group
    }
}

// ---------------- Kernel 3: deterministic final reduction ----------------
__global__ __launch_bounds__(256)
void sge_finalize(const float* __restrict__ part, const float* __restrict__ hb,
                  float* __restrict__ y)
{
    const int b = blockIdx.x * 256 + threadIdx.x;
    float s = hb[0];
    #pragma unroll
    for (int rg = 0; rg < NRG; ++rg) s += part[rg * B + b];
    y[b] = s;
}

extern "C" void kernel_launch(void* const* d_in, const int* in_sizes, int n_in,
                              void* d_out, int out_size, void* d_ws, size_t ws_size,
                              hipStream_t stream)
{
    const float* x   = (const float*)d_in[0];
    const float* th  = (const float*)d_in[1];
    const float* isp = (const float*)d_in[2];
    const float* esp = (const float*)d_in[3];
    const float* ml  = (const float*)d_in[4];
    const float* lk  = (const float*)d_in[5];
    const float* gl  = (const float*)d_in[6];
    const float* tg  = (const float*)d_in[7];
    const float* gml = (const float*)d_in[8];
    const float* kf  = (const float*)d_in[9];
    const float* hw  = (const float*)d_in[10];
    const float* hb  = (const float*)d_in[11];
    float* ws = (float*)d_ws;
    float* y  = (float*)d_out;

    sge_precompute<<<R, 256, 0, stream>>>(th, isp, esp, ml, lk, gl, tg, gml, kf, hw, ws);
    sge_main<<<dim3(NBG, NRG), 512, 0, stream>>>(x, ws, ws + OFF_PART);
    sge_finalize<<<B / 256, 256, 0, stream>>>(ws + OFF_PART, hb, y);
}